// Round 5
// baseline (224.892 us; speedup 1.0000x reference)
//
#include <hip/hip_runtime.h>
#include <hip/hip_bf16.h>
#include <stdint.h>

using f32x4  = __attribute__((ext_vector_type(4))) float;
using f32x16 = __attribute__((ext_vector_type(16))) float;
using bf16x8 = __attribute__((ext_vector_type(8))) short;

constexpr int BATCH = 4;
constexpr int LQ_   = 256;
constexpr int LK_   = 50000;
constexpr int OUTD  = 256;
constexpr int EIN   = 128;
constexpr int TKB   = 32;                     // k-rows per tile
constexpr int NKT   = (LK_ + TKB - 1) / TKB;  // 1563
constexpr int BPB   = 64;                     // blocks per batch (grid = 256)

__device__ __forceinline__ uint32_t f2bf(float f) {
  uint32_t u = __builtin_bit_cast(uint32_t, f);
  u = (u + 0x7fffu + ((u >> 16) & 1u)) >> 16;
  return u;
}

// ---- prep_all: blocks 0-63 -> Gn, 64-95 -> cast Wv, 96 -> zero num/den ----
__global__ __launch_bounds__(256) void prep_all(
    const float* __restrict__ query, const float* __restrict__ Wq,
    const float* __restrict__ bq,    const float* __restrict__ Wk,
    const float* __restrict__ Wv,    ushort* __restrict__ Gn,
    ushort* __restrict__ Wvbf,       float* __restrict__ numden)
{
  const int blk = blockIdx.x, tid = threadIdx.x;
  if (blk >= 64) {
    if (blk < 96) {                       // cast Wv -> bf16 (32 blocks x 2048)
      int base = (blk - 64) * 2048 + tid * 8;
      float4 a = *(const float4*)(Wv + base);
      float4 c = *(const float4*)(Wv + base + 4);
      uint4 pk;
      pk.x = f2bf(a.x) | (f2bf(a.y) << 16);
      pk.y = f2bf(a.z) | (f2bf(a.w) << 16);
      pk.z = f2bf(c.x) | (f2bf(c.y) << 16);
      pk.w = f2bf(c.z) | (f2bf(c.w) << 16);
      *(uint4*)(Wvbf + base) = pk;
    } else {                              // zero the atomic accumulators
      for (int i = tid; i < 2 * BATCH * OUTD; i += 256) numden[i] = 0.f;
    }
    return;
  }
  // ---- Gn[b] = (1/16)*(query[b]@Wq^T + bq)@Wk, 16 q-rows per block -------
  __shared__ float qin[16 * EIN];
  __shared__ float Qr [16 * OUTD];
  const int b = blk >> 4, q0 = (blk & 15) * 16;
  {
    int idx = tid * 8;
    int row = idx >> 7, c = idx & 127;
    const float* p = query + ((size_t)b * LQ_ + q0 + row) * EIN + c;
    float4 a = *(const float4*)p;
    float4 d = *(const float4*)(p + 4);
    float* q = &qin[row * EIN + c];
    q[0]=a.x; q[1]=a.y; q[2]=a.z; q[3]=a.w; q[4]=d.x; q[5]=d.y; q[6]=d.z; q[7]=d.w;
  }
  __syncthreads();

  float acc[16];
  {
    float bias = bq[tid];
#pragma unroll
    for (int i = 0; i < 16; ++i) acc[i] = bias;
  }
  for (int d4 = 0; d4 < EIN / 4; ++d4) {
    f32x4 w4 = *(const f32x4*)(Wq + tid * EIN + d4 * 4);
#pragma unroll
    for (int i = 0; i < 16; ++i) {
      f32x4 q4 = *(const f32x4*)(qin + i * EIN + d4 * 4);
      acc[i] += q4[0]*w4[0] + q4[1]*w4[1] + q4[2]*w4[2] + q4[3]*w4[3];
    }
  }
#pragma unroll
  for (int i = 0; i < 16; ++i) Qr[i * OUTD + tid] = acc[i];
  __syncthreads();

  float acc2[16];
#pragma unroll
  for (int i = 0; i < 16; ++i) acc2[i] = 0.f;
  for (int d4 = 0; d4 < OUTD / 4; ++d4) {
    float w0 = Wk[(d4*4+0) * OUTD + tid];
    float w1 = Wk[(d4*4+1) * OUTD + tid];
    float w2 = Wk[(d4*4+2) * OUTD + tid];
    float w3 = Wk[(d4*4+3) * OUTD + tid];
#pragma unroll
    for (int i = 0; i < 16; ++i) {
      f32x4 q4 = *(const f32x4*)(Qr + i * OUTD + d4 * 4);
      acc2[i] += q4[0]*w0 + q4[1]*w1 + q4[2]*w2 + q4[3]*w3;
    }
  }
  const float norm = 0.0625f;
#pragma unroll
  for (int i = 0; i < 16; ++i)
    Gn[((size_t)b * LQ_ + q0 + i) * OUTD + tid] = (ushort)f2bf(acc2[i] * norm);
}

// ---- main ------------------------------------------------------------------
// 256 blocks (1/CU), 1024 thr = 16 waves. Waves 0-7 (S): persistent Gn frags,
// compute S=Gn@inp^T, e=exp(S), den; publish e via LDS. Waves 8-15 (V):
// persistent Wv frags, compute Vt=Wv@inp^T, then num += e*Vt (lane-aligned:
// S-wave wq and V-wave wq+8 own the same q-rows with identical D-frag layout).
// Per-wave A-frags = 64 VGPR (one matrix) -> <=128 total -> 4 waves/SIMD.
// B-tile (input, 32 rows x 256 feats bf16, 16KB, double-buffered):
//   granule (fb 0..31, row 0..31) at fb*512 + ((row^fb)*16).
//   write: lane->(fb=t&31,row=t>>5): banks balanced. read: 32 lanes span one
//   fb region fully -> balanced. Both conflict-free in throughput.
__global__ __launch_bounds__(1024, 4) void attn_main(
    const float*  __restrict__ input, const ushort* __restrict__ Gn,
    const ushort* __restrict__ Wvbf,  float* __restrict__ num,
    float* __restrict__ den)
{
  __shared__ ushort bb[2 * 8192];     // 2 x 16 KB bf16 input tile
  __shared__ float  etile[8192];      // 32 KB: [wq][r4][lane] f32
  const int b = blockIdx.x >> 6, blk = blockIdx.x & (BPB - 1);
  const int t0 = (blk * NKT) >> 6, t1 = ((blk + 1) * NKT) >> 6;
  const int tid = threadIdx.x, w = tid >> 6, l = tid & 63;
  const int wq = w & 7;
  const bool isS = (w < 8);
  const int hi = l >> 5, lk = l & 31;
  const float* src = input + (size_t)b * LK_ * 256;

  // persistent A-fragments: one matrix per wave (64 VGPRs)
  const int arow = wq * 32 + lk;
  const ushort* ap = (isS ? (Gn + ((size_t)b * LQ_ + arow) * 256)
                          : (Wvbf + (size_t)arow * 256)) + hi * 8;
  bf16x8 af[16];
#pragma unroll
  for (int k = 0; k < 16; ++k) af[k] = *(const bf16x8*)(ap + k * 16);

  float accR[16];
#pragma unroll
  for (int r = 0; r < 16; ++r) accR[r] = 0.f;

  float4 sA0, sA1;                    // staging regs (8 f32 / thread)
  auto loadreg = [&](int t) {
    int row = t * TKB + (tid >> 5);
    row = row < LK_ ? row : LK_ - 1;  // clamp (masked via e=0)
    const float* p = src + (size_t)row * 256 + (tid & 31) * 8;
    sA0 = *(const float4*)p;
    sA1 = *(const float4*)(p + 4);
  };
  auto writebuf = [&](int buf) {
    int fb = tid & 31, row = tid >> 5;
    uint4 pk;
    pk.x = f2bf(sA0.x) | (f2bf(sA0.y) << 16);
    pk.y = f2bf(sA0.z) | (f2bf(sA0.w) << 16);
    pk.z = f2bf(sA1.x) | (f2bf(sA1.y) << 16);
    pk.w = f2bf(sA1.z) | (f2bf(sA1.w) << 16);
    *(uint4*)((char*)bb + buf * 16384 + fb * 512 + ((row ^ fb) * 16)) = pk;
  };

  loadreg(t0);
  writebuf(0);
  loadreg(t0 + 1);                    // clamped; only written if t0+1 < t1
  __syncthreads();

  char* emy = (char*)etile + wq * 4096 + l * 16;

  for (int t = t0; t < t1; ++t) {
    const int p = (t - t0) & 1;
    const char* base = (const char*)bb + p * 16384;

    f32x16 aX = {0,0,0,0,0,0,0,0,0,0,0,0,0,0,0,0};
#pragma unroll
    for (int ks = 0; ks < 16; ++ks) {
      const int fb = ks * 2 + hi;
      bf16x8 bv = *(const bf16x8*)(base + fb * 512 + ((lk ^ fb) * 16));
      aX = __builtin_amdgcn_mfma_f32_32x32x16_bf16(af[ks], bv, aX, 0, 0, 0);
    }

    if (isS) {
      const bool valid = (t * TKB + lk) < LK_;
#pragma unroll
      for (int r4 = 0; r4 < 4; ++r4) {
        f32x4 ev;
#pragma unroll
        for (int j = 0; j < 4; ++j) {
          float e = valid ? __expf(aX[r4 * 4 + j]) : 0.f;
          ev[j] = e;
          accR[r4 * 4 + j] += e;
        }
        *(f32x4*)(emy + r4 * 1024) = ev;
      }
    }
    __syncthreads();                  // barrier-A: e published, bb(t) consumed

    if (!isS) {
#pragma unroll
      for (int r4 = 0; r4 < 4; ++r4) {
        f32x4 ev = *(const f32x4*)(emy + r4 * 1024);
#pragma unroll
        for (int j = 0; j < 4; ++j)
          accR[r4 * 4 + j] += ev[j] * aX[r4 * 4 + j];
      }
    }
    if (t + 1 < t1) {
      writebuf(p ^ 1);                // regs hold tile t+1
      loadreg(t + 2);                 // issue next (clamped if past end)
    }
    __syncthreads();                  // barrier-B: bb(t+1) ready
  }

  // reduce over 32 k-lanes, one atomic per q
#pragma unroll
  for (int r = 0; r < 16; ++r) {
    float v = accR[r];
#pragma unroll
    for (int m = 1; m < 32; m <<= 1) v += __shfl_xor(v, m, 64);
    if (lk == 0) {
      int q = wq * 32 + 4 * hi + (r & 3) + 8 * (r >> 2);
      atomicAdd((isS ? den : num) + b * OUTD + q, v);
    }
  }
}

// ---- finalize: out = num/den + bv ------------------------------------------
__global__ __launch_bounds__(256) void finalize(const float* __restrict__ num,
                                                const float* __restrict__ den,
                                                const float* __restrict__ bv,
                                                float* __restrict__ out) {
  int i = blockIdx.x * 256 + threadIdx.x;
  out[i] = num[i] / den[i] + bv[i & 255];
}

extern "C" void kernel_launch(void* const* d_in, const int* in_sizes, int n_in,
                              void* d_out, int out_size, void* d_ws, size_t ws_size,
                              hipStream_t stream)
{
  const float* query = (const float*)d_in[0];
  const float* input = (const float*)d_in[1];
  const float* Wq    = (const float*)d_in[2];
  const float* bq    = (const float*)d_in[3];
  const float* Wk    = (const float*)d_in[4];
  // d_in[5] = bk : softmax-invariant, unused
  const float* Wv    = (const float*)d_in[6];
  const float* bv    = (const float*)d_in[7];
  float* out = (float*)d_out;

  char* ws = (char*)d_ws;
  ushort* Gn     = (ushort*)ws;                       // 512 KB
  ushort* Wvbf   = (ushort*)(ws + 524288);            // 128 KB
  float*  numden = (float*)(ws + 524288 + 131072);    // 8 KB
  float*  num    = numden;
  float*  den    = numden + BATCH * OUTD;

  prep_all<<<97, 256, 0, stream>>>(query, Wq, bq, Wk, Wv, Gn, Wvbf, numden);
  attn_main<<<BATCH * BPB, 1024, 0, stream>>>(input, Gn, Wvbf, num, den);
  finalize<<<BATCH, 256, 0, stream>>>(num, den, bv, out);
}